// Round 5
// baseline (2759.861 us; speedup 1.0000x reference)
//
#include <hip/hip_runtime.h>
#include <math.h>

#define BB 16
#define LL 1024
#define EE 256
#define OO 256

// ---------------------------------------------------------------------------
// Kernel 1: merged QKV projection.  One block computes the same 64x64 tile of
// q, k AND v (A-tile staged once, reused 3x -> 192 FMA per 16 LDS reads).
// grid = (M/64, O/64), block = 256 (16x16 threads, 4x4 outputs per matrix)
// ---------------------------------------------------------------------------
__global__ __launch_bounds__(256, 4) void qkv_kernel(
    const float* __restrict__ joint, const float* __restrict__ Wq,
    const float* __restrict__ Wk, const float* __restrict__ Wv,
    float* __restrict__ qout, float* __restrict__ kout, float* __restrict__ vout)
{
    const int m0 = blockIdx.x * 64;
    const int n0 = blockIdx.y * 64;

    __shared__ float As[64][36];
    __shared__ float Ws[3][32][68];

    const int tid = threadIdx.x;
    const int tx = tid & 15;
    const int ty = tid >> 4;

    float4 acc[3][4];   // [matrix][row i], 4 cols packed in float4
    #pragma unroll
    for (int w = 0; w < 3; ++w)
        #pragma unroll
        for (int i = 0; i < 4; ++i) acc[w][i] = make_float4(0.f, 0.f, 0.f, 0.f);

    for (int e0 = 0; e0 < EE; e0 += 32) {
        {
            const int r = tid >> 3;
            const int c = (tid & 7) << 2;
            *(float4*)&As[r][c]      = *(const float4*)&joint[(size_t)(m0 + r) * EE + e0 + c];
            *(float4*)&As[r + 32][c] = *(const float4*)&joint[(size_t)(m0 + r + 32) * EE + e0 + c];
            const int wr = tid >> 4;
            const int wc = tx << 2;
            *(float4*)&Ws[0][wr][wc]      = *(const float4*)&Wq[(size_t)(e0 + wr) * OO + n0 + wc];
            *(float4*)&Ws[0][wr + 16][wc] = *(const float4*)&Wq[(size_t)(e0 + wr + 16) * OO + n0 + wc];
            *(float4*)&Ws[1][wr][wc]      = *(const float4*)&Wk[(size_t)(e0 + wr) * OO + n0 + wc];
            *(float4*)&Ws[1][wr + 16][wc] = *(const float4*)&Wk[(size_t)(e0 + wr + 16) * OO + n0 + wc];
            *(float4*)&Ws[2][wr][wc]      = *(const float4*)&Wv[(size_t)(e0 + wr) * OO + n0 + wc];
            *(float4*)&Ws[2][wr + 16][wc] = *(const float4*)&Wv[(size_t)(e0 + wr + 16) * OO + n0 + wc];
        }
        __syncthreads();
        #pragma unroll
        for (int e = 0; e < 32; e += 4) {
            float4 a4[4];
            #pragma unroll
            for (int i = 0; i < 4; ++i) a4[i] = *(const float4*)&As[ty * 4 + i][e];
            #pragma unroll
            for (int w = 0; w < 3; ++w) {
                float4 w4[4];
                #pragma unroll
                for (int k = 0; k < 4; ++k) w4[k] = *(const float4*)&Ws[w][e + k][tx * 4];
                #pragma unroll
                for (int i = 0; i < 4; ++i) {
                    acc[w][i].x += a4[i].x*w4[0].x + a4[i].y*w4[1].x + a4[i].z*w4[2].x + a4[i].w*w4[3].x;
                    acc[w][i].y += a4[i].x*w4[0].y + a4[i].y*w4[1].y + a4[i].z*w4[2].y + a4[i].w*w4[3].y;
                    acc[w][i].z += a4[i].x*w4[0].z + a4[i].y*w4[1].z + a4[i].z*w4[2].z + a4[i].w*w4[3].z;
                    acc[w][i].w += a4[i].x*w4[0].w + a4[i].y*w4[1].w + a4[i].z*w4[2].w + a4[i].w*w4[3].w;
                }
            }
        }
        __syncthreads();
    }
    #pragma unroll
    for (int i = 0; i < 4; ++i) {
        const size_t off = (size_t)(m0 + ty * 4 + i) * OO + n0 + tx * 4;
        *(float4*)&qout[off] = acc[0][i];
        *(float4*)&kout[off] = acc[1][i];
        *(float4*)&vout[off] = acc[2][i];
    }
}

// ---------------------------------------------------------------------------
// Kernel 2: fused flash-style attention with delta bias + post-softmax mask.
// grid = (L/32, B), block = 256.  32 q-rows per block (2 per ty-group).
// S-column ownership: thread tx owns columns {tx, tx+16, tx+32, tx+48} of the
// 64-wide j-tile -> k-fragment LDS reads hit consecutive rows (2-way, free)
// instead of the old 8-way conflict at row-stride 4.
// Softmax denominator over ALL columns (reference masks AFTER softmax);
// p zeroed for j >= T before PV; rows i >= T zeroed at the store.
// NOTE: qm aliases outp (q lives in d_out). Safe: a block reads only its own
// 32 q-rows (all reads precede the epilogue) and writes exactly those rows.
// ---------------------------------------------------------------------------
__global__ __launch_bounds__(256, 2) void attn_kernel(
    const float* __restrict__ qm, const float* __restrict__ km,
    const float* __restrict__ vm, const float* __restrict__ delta,
    const int* __restrict__ traj_len, float* __restrict__ outp)
{
    const int b  = blockIdx.y;
    const int i0 = blockIdx.x * 32;
    const int T  = traj_len[b];
    const int tid = threadIdx.x;
    const int tx = tid & 15;
    const int ty = tid >> 4;          // 0..15, rows 2*ty+i

    __shared__ float Qs[32][68];      // 32 rows x 64-e chunk
    __shared__ float KVs[64][68];     // K e-chunk, then V col-chunk (time-shared)
    __shared__ float Ps[32][68];      // masked softmax probabilities

    float4 o[4][2];                   // [o-col chunk][row i]
    #pragma unroll
    for (int cc = 0; cc < 4; ++cc)
        #pragma unroll
        for (int i = 0; i < 2; ++i) o[cc][i] = make_float4(0.f, 0.f, 0.f, 0.f);

    float mrow[2] = {-INFINITY, -INFINITY};
    float lrow[2] = {0.f, 0.f};

    const float* __restrict__ qb = qm + (size_t)b * LL * OO;
    const float* __restrict__ kb = km + (size_t)b * LL * OO;
    const float* __restrict__ vb = vm + (size_t)b * LL * OO;

    for (int j0 = 0; j0 < LL; j0 += 64) {
        // ---- s init with delta bias: s[i][j] at column j0 + tx + 16*j
        float s[2][4];
        #pragma unroll
        for (int i = 0; i < 2; ++i) {
            const size_t rbase = (size_t)(b * LL + i0 + 2 * ty + i) * LL;
            #pragma unroll
            for (int j = 0; j < 4; ++j) {
                const float2 d = *(const float2*)&delta[(rbase + j0 + tx + 16 * j) * 2];
                s[i][j] = d.x + d.y;
            }
        }

        // ---- QK^T over e in chunks of 64
        for (int e0 = 0; e0 < OO; e0 += 64) {
            {   // stage Q rows (32x64) and K rows (64x64)
                const int qr = tid >> 3;
                const int qc = (tid & 7) << 2;
                *(float4*)&Qs[qr][qc]      = *(const float4*)&qb[(size_t)(i0 + qr) * OO + e0 + qc];
                *(float4*)&Qs[qr][qc + 32] = *(const float4*)&qb[(size_t)(i0 + qr) * OO + e0 + qc + 32];
                const int kr = tid >> 2;
                const int kc = (tid & 3) << 4;
                #pragma unroll
                for (int k = 0; k < 4; ++k)
                    *(float4*)&KVs[kr][kc + 4 * k] =
                        *(const float4*)&kb[(size_t)(j0 + kr) * OO + e0 + kc + 4 * k];
            }
            __syncthreads();
            #pragma unroll
            for (int e = 0; e < 64; e += 4) {
                float4 q4[2], k4[4];
                #pragma unroll
                for (int i = 0; i < 2; ++i) q4[i] = *(const float4*)&Qs[2 * ty + i][e];
                #pragma unroll
                for (int j = 0; j < 4; ++j) k4[j] = *(const float4*)&KVs[tx + 16 * j][e];
                #pragma unroll
                for (int i = 0; i < 2; ++i)
                    #pragma unroll
                    for (int j = 0; j < 4; ++j)
                        s[i][j] += q4[i].x*k4[j].x + q4[i].y*k4[j].y
                                 + q4[i].z*k4[j].z + q4[i].w*k4[j].w;
            }
            __syncthreads();
        }

        // ---- online softmax update (denominator over ALL columns)
        #pragma unroll
        for (int i = 0; i < 2; ++i) {
            float mx = fmaxf(fmaxf(s[i][0], s[i][1]), fmaxf(s[i][2], s[i][3]));
            #pragma unroll
            for (int d = 1; d < 16; d <<= 1) mx = fmaxf(mx, __shfl_xor(mx, d));
            const float mnew = fmaxf(mrow[i], mx);
            const float sc = __expf(mrow[i] - mnew);
            float p[4];
            float rs = 0.f;
            #pragma unroll
            for (int j = 0; j < 4; ++j) { p[j] = __expf(s[i][j] - mnew); rs += p[j]; }
            #pragma unroll
            for (int d = 1; d < 16; d <<= 1) rs += __shfl_xor(rs, d);
            lrow[i] = lrow[i] * sc + rs;
            mrow[i] = mnew;
            #pragma unroll
            for (int j = 0; j < 4; ++j) {
                if (j0 + tx + 16 * j >= T) p[j] = 0.f;   // post-softmax mask
                Ps[2 * ty + i][tx + 16 * j] = p[j];
            }
            #pragma unroll
            for (int cc = 0; cc < 4; ++cc) {
                o[cc][i].x *= sc; o[cc][i].y *= sc; o[cc][i].z *= sc; o[cc][i].w *= sc;
            }
        }

        // ---- PV: 4 o-column chunks of 64
        #pragma unroll
        for (int cc = 0; cc < 4; ++cc) {
            {   // stage V chunk (64 rows x 64 o-cols); overwrites K region
                const int vr = tid >> 2;
                const int vc = (tid & 3) << 4;
                #pragma unroll
                for (int k = 0; k < 4; ++k)
                    *(float4*)&KVs[vr][vc + 4 * k] =
                        *(const float4*)&vb[(size_t)(j0 + vr) * OO + cc * 64 + vc + 4 * k];
            }
            __syncthreads();   // publishes Ps (cc==0) and V chunk
            #pragma unroll
            for (int jj = 0; jj < 64; jj += 4) {
                float4 p4[2], v4[4];
                #pragma unroll
                for (int i = 0; i < 2; ++i) p4[i] = *(const float4*)&Ps[2 * ty + i][jj];
                #pragma unroll
                for (int k = 0; k < 4; ++k) v4[k] = *(const float4*)&KVs[jj + k][tx * 4];
                #pragma unroll
                for (int i = 0; i < 2; ++i) {
                    o[cc][i].x += p4[i].x*v4[0].x + p4[i].y*v4[1].x + p4[i].z*v4[2].x + p4[i].w*v4[3].x;
                    o[cc][i].y += p4[i].x*v4[0].y + p4[i].y*v4[1].y + p4[i].z*v4[2].y + p4[i].w*v4[3].y;
                    o[cc][i].z += p4[i].x*v4[0].z + p4[i].y*v4[1].z + p4[i].z*v4[2].z + p4[i].w*v4[3].z;
                    o[cc][i].w += p4[i].x*v4[0].w + p4[i].y*v4[1].w + p4[i].z*v4[2].w + p4[i].w*v4[3].w;
                }
            }
            __syncthreads();
        }
    }

    // ---- epilogue: normalize, zero invalid rows, store (overwrites this
    // block's own q rows only)
    #pragma unroll
    for (int i = 0; i < 2; ++i) {
        const int r = i0 + 2 * ty + i;
        const float inv = 1.f / lrow[i];
        const bool rv = (r < T);
        #pragma unroll
        for (int cc = 0; cc < 4; ++cc) {
            float4 res;
            res.x = rv ? o[cc][i].x * inv : 0.f;
            res.y = rv ? o[cc][i].y * inv : 0.f;
            res.z = rv ? o[cc][i].z * inv : 0.f;
            res.w = rv ? o[cc][i].w * inv : 0.f;
            *(float4*)&outp[(size_t)(b * LL + r) * OO + cc * 64 + tx * 4] = res;
        }
    }
}

// ---------------------------------------------------------------------------
extern "C" void kernel_launch(void* const* d_in, const int* in_sizes, int n_in,
                              void* d_out, int out_size, void* d_ws, size_t ws_size,
                              hipStream_t stream)
{
    const float* joint    = (const float*)d_in[0];
    const float* delta    = (const float*)d_in[1];
    const int*   traj_len = (const int*)d_in[2];
    const float* Wq       = (const float*)d_in[3];
    const float* Wk       = (const float*)d_in[4];
    const float* Wv       = (const float*)d_in[5];
    float* outp = (float*)d_out;

    const size_t stride = (size_t)BB * LL * OO;   // 4M elements = 16 MB
    float* q = outp;                 // q lives in d_out (16 MB)
    float* k = (float*)d_ws;         // k: ws[0 .. 16MB)
    float* v = k + stride;           // v: ws[16MB .. 32MB)

    dim3 g1(BB * LL / 64, OO / 64);
    qkv_kernel<<<g1, 256, 0, stream>>>(joint, Wq, Wk, Wv, q, k, v);

    dim3 g2(LL / 32, BB);
    attn_kernel<<<g2, 256, 0, stream>>>(q, k, v, delta, traj_len, outp);
}

// Round 6
// 776.133 us; speedup vs baseline: 3.5559x; 3.5559x over previous
//
#include <hip/hip_runtime.h>
#include <math.h>

#define BB 16
#define LL 1024
#define EE 256
#define OO 256

// ---------------------------------------------------------------------------
// Kernel 1: merged QKV projection.  One block computes the same 64x64 tile of
// q, k AND v (A-tile staged once, reused 3x -> 192 FMA per 16 LDS reads).
// grid = (M/64, O/64), block = 256 (16x16 threads, 4x4 outputs per matrix).
// NOTE: plain __launch_bounds__(256) — the merged kernel needs ~110+ VGPRs
// (48 for acc[3][4] float4 alone); the previous (256,4) min-waves spec capped
// VGPRs at 64 and spilled the accumulators to scratch -> 8 GB of HBM spill
// traffic, 2.27 ms (R5 counters: WRITE_SIZE 4.1 GB vs 50 MB of real stores).
// ---------------------------------------------------------------------------
__global__ __launch_bounds__(256) void qkv_kernel(
    const float* __restrict__ joint, const float* __restrict__ Wq,
    const float* __restrict__ Wk, const float* __restrict__ Wv,
    float* __restrict__ qout, float* __restrict__ kout, float* __restrict__ vout)
{
    const int m0 = blockIdx.x * 64;
    const int n0 = blockIdx.y * 64;

    __shared__ float As[64][36];
    __shared__ float Ws[3][32][68];

    const int tid = threadIdx.x;
    const int tx = tid & 15;
    const int ty = tid >> 4;

    float4 acc[3][4];   // [matrix][row i], 4 cols packed in float4
    #pragma unroll
    for (int w = 0; w < 3; ++w)
        #pragma unroll
        for (int i = 0; i < 4; ++i) acc[w][i] = make_float4(0.f, 0.f, 0.f, 0.f);

    for (int e0 = 0; e0 < EE; e0 += 32) {
        {
            const int r = tid >> 3;
            const int c = (tid & 7) << 2;
            *(float4*)&As[r][c]      = *(const float4*)&joint[(size_t)(m0 + r) * EE + e0 + c];
            *(float4*)&As[r + 32][c] = *(const float4*)&joint[(size_t)(m0 + r + 32) * EE + e0 + c];
            const int wr = tid >> 4;
            const int wc = tx << 2;
            *(float4*)&Ws[0][wr][wc]      = *(const float4*)&Wq[(size_t)(e0 + wr) * OO + n0 + wc];
            *(float4*)&Ws[0][wr + 16][wc] = *(const float4*)&Wq[(size_t)(e0 + wr + 16) * OO + n0 + wc];
            *(float4*)&Ws[1][wr][wc]      = *(const float4*)&Wk[(size_t)(e0 + wr) * OO + n0 + wc];
            *(float4*)&Ws[1][wr + 16][wc] = *(const float4*)&Wk[(size_t)(e0 + wr + 16) * OO + n0 + wc];
            *(float4*)&Ws[2][wr][wc]      = *(const float4*)&Wv[(size_t)(e0 + wr) * OO + n0 + wc];
            *(float4*)&Ws[2][wr + 16][wc] = *(const float4*)&Wv[(size_t)(e0 + wr + 16) * OO + n0 + wc];
        }
        __syncthreads();
        #pragma unroll
        for (int e = 0; e < 32; e += 4) {
            float4 a4[4];
            #pragma unroll
            for (int i = 0; i < 4; ++i) a4[i] = *(const float4*)&As[ty * 4 + i][e];
            #pragma unroll
            for (int w = 0; w < 3; ++w) {
                float4 w4[4];
                #pragma unroll
                for (int k = 0; k < 4; ++k) w4[k] = *(const float4*)&Ws[w][e + k][tx * 4];
                #pragma unroll
                for (int i = 0; i < 4; ++i) {
                    acc[w][i].x += a4[i].x*w4[0].x + a4[i].y*w4[1].x + a4[i].z*w4[2].x + a4[i].w*w4[3].x;
                    acc[w][i].y += a4[i].x*w4[0].y + a4[i].y*w4[1].y + a4[i].z*w4[2].y + a4[i].w*w4[3].y;
                    acc[w][i].z += a4[i].x*w4[0].z + a4[i].y*w4[1].z + a4[i].z*w4[2].z + a4[i].w*w4[3].z;
                    acc[w][i].w += a4[i].x*w4[0].w + a4[i].y*w4[1].w + a4[i].z*w4[2].w + a4[i].w*w4[3].w;
                }
            }
        }
        __syncthreads();
    }
    #pragma unroll
    for (int i = 0; i < 4; ++i) {
        const size_t off = (size_t)(m0 + ty * 4 + i) * OO + n0 + tx * 4;
        *(float4*)&qout[off] = acc[0][i];
        *(float4*)&kout[off] = acc[1][i];
        *(float4*)&vout[off] = acc[2][i];
    }
}

// ---------------------------------------------------------------------------
// Kernel 2: fused flash-style attention with delta bias + post-softmax mask.
// grid = (L/32, B), block = 256.  32 q-rows per block (2 per ty-group).
// S-column ownership: thread tx owns columns {tx, tx+16, tx+32, tx+48} of the
// 64-wide j-tile -> k-fragment LDS reads hit consecutive rows (2-way, free)
// instead of the old 8-way conflict at row-stride 4.
// Softmax denominator over ALL columns (reference masks AFTER softmax);
// p zeroed for j >= T before PV; rows i >= T zeroed at the store.
// NOTE: qm aliases outp (q lives in d_out). Safe: a block reads only its own
// 32 q-rows (all reads precede the epilogue) and writes exactly those rows.
// ---------------------------------------------------------------------------
__global__ __launch_bounds__(256, 2) void attn_kernel(
    const float* __restrict__ qm, const float* __restrict__ km,
    const float* __restrict__ vm, const float* __restrict__ delta,
    const int* __restrict__ traj_len, float* __restrict__ outp)
{
    const int b  = blockIdx.y;
    const int i0 = blockIdx.x * 32;
    const int T  = traj_len[b];
    const int tid = threadIdx.x;
    const int tx = tid & 15;
    const int ty = tid >> 4;          // 0..15, rows 2*ty+i

    __shared__ float Qs[32][68];      // 32 rows x 64-e chunk
    __shared__ float KVs[64][68];     // K e-chunk, then V col-chunk (time-shared)
    __shared__ float Ps[32][68];      // masked softmax probabilities

    float4 o[4][2];                   // [o-col chunk][row i]
    #pragma unroll
    for (int cc = 0; cc < 4; ++cc)
        #pragma unroll
        for (int i = 0; i < 2; ++i) o[cc][i] = make_float4(0.f, 0.f, 0.f, 0.f);

    float mrow[2] = {-INFINITY, -INFINITY};
    float lrow[2] = {0.f, 0.f};

    const float* __restrict__ qb = qm + (size_t)b * LL * OO;
    const float* __restrict__ kb = km + (size_t)b * LL * OO;
    const float* __restrict__ vb = vm + (size_t)b * LL * OO;

    for (int j0 = 0; j0 < LL; j0 += 64) {
        // ---- s init with delta bias: s[i][j] at column j0 + tx + 16*j
        float s[2][4];
        #pragma unroll
        for (int i = 0; i < 2; ++i) {
            const size_t rbase = (size_t)(b * LL + i0 + 2 * ty + i) * LL;
            #pragma unroll
            for (int j = 0; j < 4; ++j) {
                const float2 d = *(const float2*)&delta[(rbase + j0 + tx + 16 * j) * 2];
                s[i][j] = d.x + d.y;
            }
        }

        // ---- QK^T over e in chunks of 64
        for (int e0 = 0; e0 < OO; e0 += 64) {
            {   // stage Q rows (32x64) and K rows (64x64)
                const int qr = tid >> 3;
                const int qc = (tid & 7) << 2;
                *(float4*)&Qs[qr][qc]      = *(const float4*)&qb[(size_t)(i0 + qr) * OO + e0 + qc];
                *(float4*)&Qs[qr][qc + 32] = *(const float4*)&qb[(size_t)(i0 + qr) * OO + e0 + qc + 32];
                const int kr = tid >> 2;
                const int kc = (tid & 3) << 4;
                #pragma unroll
                for (int k = 0; k < 4; ++k)
                    *(float4*)&KVs[kr][kc + 4 * k] =
                        *(const float4*)&kb[(size_t)(j0 + kr) * OO + e0 + kc + 4 * k];
            }
            __syncthreads();
            #pragma unroll
            for (int e = 0; e < 64; e += 4) {
                float4 q4[2], k4[4];
                #pragma unroll
                for (int i = 0; i < 2; ++i) q4[i] = *(const float4*)&Qs[2 * ty + i][e];
                #pragma unroll
                for (int j = 0; j < 4; ++j) k4[j] = *(const float4*)&KVs[tx + 16 * j][e];
                #pragma unroll
                for (int i = 0; i < 2; ++i)
                    #pragma unroll
                    for (int j = 0; j < 4; ++j)
                        s[i][j] += q4[i].x*k4[j].x + q4[i].y*k4[j].y
                                 + q4[i].z*k4[j].z + q4[i].w*k4[j].w;
            }
            __syncthreads();
        }

        // ---- online softmax update (denominator over ALL columns)
        #pragma unroll
        for (int i = 0; i < 2; ++i) {
            float mx = fmaxf(fmaxf(s[i][0], s[i][1]), fmaxf(s[i][2], s[i][3]));
            #pragma unroll
            for (int d = 1; d < 16; d <<= 1) mx = fmaxf(mx, __shfl_xor(mx, d));
            const float mnew = fmaxf(mrow[i], mx);
            const float sc = __expf(mrow[i] - mnew);
            float p[4];
            float rs = 0.f;
            #pragma unroll
            for (int j = 0; j < 4; ++j) { p[j] = __expf(s[i][j] - mnew); rs += p[j]; }
            #pragma unroll
            for (int d = 1; d < 16; d <<= 1) rs += __shfl_xor(rs, d);
            lrow[i] = lrow[i] * sc + rs;
            mrow[i] = mnew;
            #pragma unroll
            for (int j = 0; j < 4; ++j) {
                if (j0 + tx + 16 * j >= T) p[j] = 0.f;   // post-softmax mask
                Ps[2 * ty + i][tx + 16 * j] = p[j];
            }
            #pragma unroll
            for (int cc = 0; cc < 4; ++cc) {
                o[cc][i].x *= sc; o[cc][i].y *= sc; o[cc][i].z *= sc; o[cc][i].w *= sc;
            }
        }

        // ---- PV: 4 o-column chunks of 64
        #pragma unroll
        for (int cc = 0; cc < 4; ++cc) {
            {   // stage V chunk (64 rows x 64 o-cols); overwrites K region
                const int vr = tid >> 2;
                const int vc = (tid & 3) << 4;
                #pragma unroll
                for (int k = 0; k < 4; ++k)
                    *(float4*)&KVs[vr][vc + 4 * k] =
                        *(const float4*)&vb[(size_t)(j0 + vr) * OO + cc * 64 + vc + 4 * k];
            }
            __syncthreads();   // publishes Ps (cc==0) and V chunk
            #pragma unroll
            for (int jj = 0; jj < 64; jj += 4) {
                float4 p4[2], v4[4];
                #pragma unroll
                for (int i = 0; i < 2; ++i) p4[i] = *(const float4*)&Ps[2 * ty + i][jj];
                #pragma unroll
                for (int k = 0; k < 4; ++k) v4[k] = *(const float4*)&KVs[jj + k][tx * 4];
                #pragma unroll
                for (int i = 0; i < 2; ++i) {
                    o[cc][i].x += p4[i].x*v4[0].x + p4[i].y*v4[1].x + p4[i].z*v4[2].x + p4[i].w*v4[3].x;
                    o[cc][i].y += p4[i].x*v4[0].y + p4[i].y*v4[1].y + p4[i].z*v4[2].y + p4[i].w*v4[3].y;
                    o[cc][i].z += p4[i].x*v4[0].z + p4[i].y*v4[1].z + p4[i].z*v4[2].z + p4[i].w*v4[3].z;
                    o[cc][i].w += p4[i].x*v4[0].w + p4[i].y*v4[1].w + p4[i].z*v4[2].w + p4[i].w*v4[3].w;
                }
            }
            __syncthreads();
        }
    }

    // ---- epilogue: normalize, zero invalid rows, store (overwrites this
    // block's own q rows only)
    #pragma unroll
    for (int i = 0; i < 2; ++i) {
        const int r = i0 + 2 * ty + i;
        const float inv = 1.f / lrow[i];
        const bool rv = (r < T);
        #pragma unroll
        for (int cc = 0; cc < 4; ++cc) {
            float4 res;
            res.x = rv ? o[cc][i].x * inv : 0.f;
            res.y = rv ? o[cc][i].y * inv : 0.f;
            res.z = rv ? o[cc][i].z * inv : 0.f;
            res.w = rv ? o[cc][i].w * inv : 0.f;
            *(float4*)&outp[(size_t)(b * LL + r) * OO + cc * 64 + tx * 4] = res;
        }
    }
}

// ---------------------------------------------------------------------------
extern "C" void kernel_launch(void* const* d_in, const int* in_sizes, int n_in,
                              void* d_out, int out_size, void* d_ws, size_t ws_size,
                              hipStream_t stream)
{
    const float* joint    = (const float*)d_in[0];
    const float* delta    = (const float*)d_in[1];
    const int*   traj_len = (const int*)d_in[2];
    const float* Wq       = (const float*)d_in[3];
    const float* Wk       = (const float*)d_in[4];
    const float* Wv       = (const float*)d_in[5];
    float* outp = (float*)d_out;

    const size_t stride = (size_t)BB * LL * OO;   // 4M elements = 16 MB
    float* q = outp;                 // q lives in d_out (16 MB)
    float* k = (float*)d_ws;         // k: ws[0 .. 16MB)
    float* v = k + stride;           // v: ws[16MB .. 32MB)

    dim3 g1(BB * LL / 64, OO / 64);
    qkv_kernel<<<g1, 256, 0, stream>>>(joint, Wq, Wk, Wv, q, k, v);

    dim3 g2(LL / 32, BB);
    attn_kernel<<<g2, 256, 0, stream>>>(q, k, v, delta, traj_len, outp);
}

// Round 7
// 559.292 us; speedup vs baseline: 4.9346x; 1.3877x over previous
//
#include <hip/hip_runtime.h>
#include <math.h>

#define BB 16
#define LL 1024
#define EE 256
#define OO 256

typedef __attribute__((ext_vector_type(8))) short short8v;   // 8 bf16 = 4 VGPR
typedef __attribute__((ext_vector_type(4))) float f32x4;     // MFMA C/D

#define MFMA16(a, b, c) __builtin_amdgcn_mfma_f32_16x16x32_bf16((a), (b), (c), 0, 0, 0)

__device__ __forceinline__ unsigned short bf16h(float x) {
    union { float f; unsigned u; } c; c.f = x;
    return (unsigned short)(c.u >> 16);
}
__device__ __forceinline__ float bf16f(unsigned short h) {
    union { unsigned u; float f; } c; c.u = ((unsigned)h) << 16;
    return c.f;
}

// read 16B (8 bf16) from LDS as 2x b64 (rows are 8B-aligned at stride 72)
__device__ __forceinline__ short8v lds_frag(const unsigned short* p) {
    union { unsigned u[4]; short8v v; } c;
    const uint2 a = *(const uint2*)p;
    const uint2 b = *(const uint2*)(p + 4);
    c.u[0] = a.x; c.u[1] = a.y; c.u[2] = b.x; c.u[3] = b.y;
    return c.v;
}

// ---------------------------------------------------------------------------
// Kernel 1: merged QKV projection (fp32 compute loop unchanged from R6).
// Epilogue: q -> fp32 into d_out; k -> split-bf16 (khi,klo); v -> split-bf16
// TRANSPOSED (vthi,vtlo as [B][O][L]) for the MFMA attention's B-operands.
// ws usage: khi(8MB) klo(8MB) vthi(8MB) vtlo(8MB) = 32MB (proven-safe size).
// ---------------------------------------------------------------------------
__global__ __launch_bounds__(256) void qkv_kernel(
    const float* __restrict__ joint, const float* __restrict__ Wq,
    const float* __restrict__ Wk, const float* __restrict__ Wv,
    float* __restrict__ qout,
    unsigned short* __restrict__ khi, unsigned short* __restrict__ klo,
    unsigned short* __restrict__ vthi, unsigned short* __restrict__ vtlo)
{
    const int m0 = blockIdx.x * 64;
    const int n0 = blockIdx.y * 64;

    __shared__ float As[64][36];
    __shared__ float Ws[3][32][68];

    const int tid = threadIdx.x;
    const int tx = tid & 15;
    const int ty = tid >> 4;

    float4 acc[3][4];
    #pragma unroll
    for (int w = 0; w < 3; ++w)
        #pragma unroll
        for (int i = 0; i < 4; ++i) acc[w][i] = make_float4(0.f, 0.f, 0.f, 0.f);

    for (int e0 = 0; e0 < EE; e0 += 32) {
        {
            const int r = tid >> 3;
            const int c = (tid & 7) << 2;
            *(float4*)&As[r][c]      = *(const float4*)&joint[(size_t)(m0 + r) * EE + e0 + c];
            *(float4*)&As[r + 32][c] = *(const float4*)&joint[(size_t)(m0 + r + 32) * EE + e0 + c];
            const int wr = tid >> 4;
            const int wc = tx << 2;
            *(float4*)&Ws[0][wr][wc]      = *(const float4*)&Wq[(size_t)(e0 + wr) * OO + n0 + wc];
            *(float4*)&Ws[0][wr + 16][wc] = *(const float4*)&Wq[(size_t)(e0 + wr + 16) * OO + n0 + wc];
            *(float4*)&Ws[1][wr][wc]      = *(const float4*)&Wk[(size_t)(e0 + wr) * OO + n0 + wc];
            *(float4*)&Ws[1][wr + 16][wc] = *(const float4*)&Wk[(size_t)(e0 + wr + 16) * OO + n0 + wc];
            *(float4*)&Ws[2][wr][wc]      = *(const float4*)&Wv[(size_t)(e0 + wr) * OO + n0 + wc];
            *(float4*)&Ws[2][wr + 16][wc] = *(const float4*)&Wv[(size_t)(e0 + wr + 16) * OO + n0 + wc];
        }
        __syncthreads();
        #pragma unroll
        for (int e = 0; e < 32; e += 4) {
            float4 a4[4];
            #pragma unroll
            for (int i = 0; i < 4; ++i) a4[i] = *(const float4*)&As[ty * 4 + i][e];
            #pragma unroll
            for (int w = 0; w < 3; ++w) {
                float4 w4[4];
                #pragma unroll
                for (int k = 0; k < 4; ++k) w4[k] = *(const float4*)&Ws[w][e + k][tx * 4];
                #pragma unroll
                for (int i = 0; i < 4; ++i) {
                    acc[w][i].x += a4[i].x*w4[0].x + a4[i].y*w4[1].x + a4[i].z*w4[2].x + a4[i].w*w4[3].x;
                    acc[w][i].y += a4[i].x*w4[0].y + a4[i].y*w4[1].y + a4[i].z*w4[2].y + a4[i].w*w4[3].y;
                    acc[w][i].z += a4[i].x*w4[0].z + a4[i].y*w4[1].z + a4[i].z*w4[2].z + a4[i].w*w4[3].z;
                    acc[w][i].w += a4[i].x*w4[0].w + a4[i].y*w4[1].w + a4[i].z*w4[2].w + a4[i].w*w4[3].w;
                }
            }
        }
        __syncthreads();
    }

    // ---- epilogue: q fp32; k split; v split transposed
    #pragma unroll
    for (int i = 0; i < 4; ++i) {
        const size_t off = (size_t)(m0 + ty * 4 + i) * OO + n0 + tx * 4;
        *(float4*)&qout[off] = acc[0][i];
        union { float4 v; float f[4]; } kk; kk.v = acc[1][i];
        union { unsigned short s[4]; ushort4 v; } h4, l4;
        #pragma unroll
        for (int j = 0; j < 4; ++j) {
            const unsigned short h = bf16h(kk.f[j]);
            h4.s[j] = h;
            l4.s[j] = bf16h(kk.f[j] - bf16f(h));
        }
        *(ushort4*)&khi[off] = h4.v;
        *(ushort4*)&klo[off] = l4.v;
    }
    {
        const int bb   = m0 >> 10;               // batch (64 | 1024, never crosses)
        const int mloc = (m0 & 1023) + ty * 4;
        union { float4 v; float f[4]; } vv[4];
        #pragma unroll
        for (int i = 0; i < 4; ++i) vv[i].v = acc[2][i];
        #pragma unroll
        for (int j = 0; j < 4; ++j) {
            const int o = n0 + tx * 4 + j;
            union { unsigned short s[4]; ushort4 v; } h4, l4;
            #pragma unroll
            for (int i = 0; i < 4; ++i) {
                const unsigned short h = bf16h(vv[i].f[j]);
                h4.s[i] = h;
                l4.s[i] = bf16h(vv[i].f[j] - bf16f(h));
            }
            const size_t toff = ((size_t)bb * OO + o) * LL + mloc;
            *(ushort4*)&vthi[toff] = h4.v;
            *(ushort4*)&vtlo[toff] = l4.v;
        }
    }
}

// ---------------------------------------------------------------------------
// Kernel 2: MFMA flash attention with split-bf16 (hi/lo) operands.
// grid = (L/32, B), block = 256 = 4 waves.
// Wave w: rh = w>>1 owns rows i0+rh*16..+16; os = w&1 splits PV col-tiles.
// QK^T: S = Qhi*Khi + Qhi*Klo + Qlo*Khi  (error ~2^-16 relative).
// PV:   O += Phi*Vhi + Phi*Vlo + Plo*Vhi.
// Bias: delta sum loaded directly into the MFMA C operand.
// Softmax denominator over ALL columns (reference masks AFTER softmax);
// P zeroed for j >= T before PV; rows i >= T zeroed at the store.
// Layouts (mfma_f32_16x16x32_bf16): A row = lane&15, k = (lane>>4)*8+e;
// B col = lane&15, k = (lane>>4)*8+e; D col = lane&15, row = (lane>>4)*4+reg.
// NOTE: qm aliases outp (q fp32 in d_out): block reads only its own 32 rows
// in the prologue and writes exactly those rows in the epilogue.
// ---------------------------------------------------------------------------
__global__ __launch_bounds__(256) void attn_mfma(
    const float* __restrict__ qm,
    const unsigned short* __restrict__ khi, const unsigned short* __restrict__ klo,
    const unsigned short* __restrict__ vthi, const unsigned short* __restrict__ vtlo,
    const float* __restrict__ delta, const int* __restrict__ traj_len,
    float* __restrict__ outp)
{
    const int b  = blockIdx.y;
    const int i0 = blockIdx.x * 32;
    const int T  = traj_len[b];
    const int tid  = threadIdx.x;
    const int lane = tid & 63;
    const int w    = tid >> 6;
    const int rh   = w >> 1;
    const int os   = w & 1;
    const int g    = lane >> 4;
    const int lr   = lane & 15;

    __shared__ unsigned short KVh[64][72];   // K e-chunk hi, then V^T hi (time-shared)
    __shared__ unsigned short KVl[64][72];   // lo counterpart
    __shared__ unsigned short Ph[32][72];    // P hi (bf16)
    __shared__ unsigned short Pl[32][72];    // P lo

    // ---- Q prologue: hi/lo A-fragments in registers (row = lr)
    short8v qhv[8], qlv[8];
    {
        const float* qrow = qm + (size_t)(b * LL + i0 + rh * 16 + lr) * OO;
        #pragma unroll
        for (int c = 0; c < 8; ++c) {
            union { float4 q[2]; float f[8]; } qq;
            qq.q[0] = *(const float4*)(qrow + c * 32 + g * 8);
            qq.q[1] = *(const float4*)(qrow + c * 32 + g * 8 + 4);
            union { unsigned short s[8]; short8v v; } hi, lo;
            #pragma unroll
            for (int e = 0; e < 8; ++e) {
                const unsigned short h = bf16h(qq.f[e]);
                hi.s[e] = h;
                lo.s[e] = bf16h(qq.f[e] - bf16f(h));
            }
            qhv[c] = hi.v; qlv[c] = lo.v;
        }
    }

    f32x4 o_acc[8];
    #pragma unroll
    for (int a = 0; a < 8; ++a) o_acc[a] = (f32x4){0.f, 0.f, 0.f, 0.f};
    float mrow[4] = {-INFINITY, -INFINITY, -INFINITY, -INFINITY};
    float lrow[4] = {0.f, 0.f, 0.f, 0.f};

    const int strow = tid >> 2;          // staging: row 0..63
    const int stcb  = (tid & 3) << 4;    // staging: col block 0/16/32/48

    for (int j0 = 0; j0 < LL; j0 += 64) {
        // ---- S init from delta bias (C-operand layout)
        f32x4 s_acc[4];
        #pragma unroll
        for (int ct = 0; ct < 4; ++ct) {
            const int j = j0 + ct * 16 + lr;
            #pragma unroll
            for (int r = 0; r < 4; ++r) {
                const int i = i0 + rh * 16 + g * 4 + r;
                const float2 d = *(const float2*)&delta[((size_t)(b * LL + i) * LL + j) * 2];
                s_acc[ct][r] = d.x + d.y;
            }
        }

        // ---- QK^T over e in 4 chunks of 64
        for (int ec = 0; ec < 4; ++ec) {
            __syncthreads();   // previous KV reads done before overwrite
            {
                const size_t src = ((size_t)(b * LL + j0 + strow)) * OO + ec * 64 + stcb;
                #pragma unroll
                for (int cc = 0; cc < 4; ++cc) {
                    *(uint2*)&KVh[strow][stcb + cc * 4] = *(const uint2*)&khi[src + cc * 4];
                    *(uint2*)&KVl[strow][stcb + cc * 4] = *(const uint2*)&klo[src + cc * 4];
                }
            }
            __syncthreads();
            #pragma unroll
            for (int sub = 0; sub < 2; ++sub) {
                const short8v qh = qhv[ec * 2 + sub];
                const short8v ql = qlv[ec * 2 + sub];
                #pragma unroll
                for (int ct = 0; ct < 4; ++ct) {
                    const short8v kh = lds_frag(&KVh[ct * 16 + lr][sub * 32 + g * 8]);
                    const short8v kl = lds_frag(&KVl[ct * 16 + lr][sub * 32 + g * 8]);
                    s_acc[ct] = MFMA16(qh, kh, s_acc[ct]);
                    s_acc[ct] = MFMA16(qh, kl, s_acc[ct]);
                    s_acc[ct] = MFMA16(ql, kh, s_acc[ct]);
                }
            }
        }

        // ---- online softmax (16-lane-group reduction; denominator unmasked)
        #pragma unroll
        for (int r = 0; r < 4; ++r) {
            float mx = fmaxf(fmaxf(s_acc[0][r], s_acc[1][r]),
                             fmaxf(s_acc[2][r], s_acc[3][r]));
            #pragma unroll
            for (int d = 1; d < 16; d <<= 1) mx = fmaxf(mx, __shfl_xor(mx, d));
            const float mnew = fmaxf(mrow[r], mx);
            const float sc = __expf(mrow[r] - mnew);
            float p[4], rs = 0.f;
            #pragma unroll
            for (int ct = 0; ct < 4; ++ct) { p[ct] = __expf(s_acc[ct][r] - mnew); rs += p[ct]; }
            #pragma unroll
            for (int d = 1; d < 16; d <<= 1) rs += __shfl_xor(rs, d);
            lrow[r] = lrow[r] * sc + rs;
            mrow[r] = mnew;
            const int prow = rh * 16 + g * 4 + r;
            #pragma unroll
            for (int ct = 0; ct < 4; ++ct) {
                const float pm = (j0 + ct * 16 + lr >= T) ? 0.f : p[ct];  // post-softmax mask
                const unsigned short h = bf16h(pm);
                Ph[prow][ct * 16 + lr] = h;
                Pl[prow][ct * 16 + lr] = bf16h(pm - bf16f(h));
            }
            #pragma unroll
            for (int a = 0; a < 8; ++a) o_acc[a][r] *= sc;
        }

        // ---- PV: 4 o-chunks of 64 (V^T staged hi/lo; barrier also orders P)
        for (int oc = 0; oc < 4; ++oc) {
            __syncthreads();
            {
                const size_t src = ((size_t)(b * OO + oc * 64 + strow)) * LL + j0 + stcb;
                #pragma unroll
                for (int cc = 0; cc < 4; ++cc) {
                    *(uint2*)&KVh[strow][stcb + cc * 4] = *(const uint2*)&vthi[src + cc * 4];
                    *(uint2*)&KVl[strow][stcb + cc * 4] = *(const uint2*)&vtlo[src + cc * 4];
                }
            }
            __syncthreads();
            #pragma unroll
            for (int jc = 0; jc < 2; ++jc) {
                const short8v ph = lds_frag(&Ph[rh * 16 + lr][jc * 32 + g * 8]);
                const short8v pl = lds_frag(&Pl[rh * 16 + lr][jc * 32 + g * 8]);
                #pragma unroll
                for (int t2 = 0; t2 < 2; ++t2) {
                    const int ct2 = os + 2 * t2;
                    const int a = oc * 2 + t2;
                    const short8v vh = lds_frag(&KVh[ct2 * 16 + lr][jc * 32 + g * 8]);
                    const short8v vl = lds_frag(&KVl[ct2 * 16 + lr][jc * 32 + g * 8]);
                    o_acc[a] = MFMA16(ph, vh, o_acc[a]);
                    o_acc[a] = MFMA16(ph, vl, o_acc[a]);
                    o_acc[a] = MFMA16(pl, vh, o_acc[a]);
                }
            }
        }
    }

    // ---- epilogue: normalize, zero invalid rows, store (own rows only)
    float inv[4];
    #pragma unroll
    for (int r = 0; r < 4; ++r) inv[r] = 1.f / lrow[r];
    #pragma unroll
    for (int oc = 0; oc < 4; ++oc) {
        #pragma unroll
        for (int t2 = 0; t2 < 2; ++t2) {
            const int a = oc * 2 + t2;
            const int o = oc * 64 + (os + 2 * t2) * 16 + lr;
            #pragma unroll
            for (int r = 0; r < 4; ++r) {
                const int i = i0 + rh * 16 + g * 4 + r;
                outp[(size_t)(b * LL + i) * OO + o] = (i < T) ? o_acc[a][r] * inv[r] : 0.f;
            }
        }
    }
}

// ---------------------------------------------------------------------------
extern "C" void kernel_launch(void* const* d_in, const int* in_sizes, int n_in,
                              void* d_out, int out_size, void* d_ws, size_t ws_size,
                              hipStream_t stream)
{
    const float* joint    = (const float*)d_in[0];
    const float* delta    = (const float*)d_in[1];
    const int*   traj_len = (const int*)d_in[2];
    const float* Wq       = (const float*)d_in[3];
    const float* Wk       = (const float*)d_in[4];
    const float* Wv       = (const float*)d_in[5];
    float* outp = (float*)d_out;

    const size_t stride = (size_t)BB * LL * OO;       // 4M elements
    float* q = outp;                                   // q fp32 in d_out
    unsigned short* khi  = (unsigned short*)d_ws;      // 8MB each
    unsigned short* klo  = khi + stride;
    unsigned short* vthi = klo + stride;
    unsigned short* vtlo = vthi + stride;              // total 32MB ws

    dim3 g1(BB * LL / 64, OO / 64);
    qkv_kernel<<<g1, 256, 0, stream>>>(joint, Wq, Wk, Wv, q, khi, klo, vthi, vtlo);

    dim3 g2(LL / 32, BB);
    attn_mfma<<<g2, 256, 0, stream>>>(q, khi, klo, vthi, vtlo, delta, traj_len, outp);
}

// Round 9
// 379.727 us; speedup vs baseline: 7.2680x; 1.4729x over previous
//
#include <hip/hip_runtime.h>
#include <math.h>

#define BB 16
#define LL 1024
#define EE 256
#define OO 256

typedef __attribute__((ext_vector_type(8))) short short8v;   // 8 bf16 = 4 VGPR
typedef __attribute__((ext_vector_type(4))) float f32x4;     // MFMA C/D

#define MFMA16(a, b, c) __builtin_amdgcn_mfma_f32_16x16x32_bf16((a), (b), (c), 0, 0, 0)

__device__ __forceinline__ unsigned short bf16h(float x) {
    union { float f; unsigned u; } c; c.f = x;
    return (unsigned short)(c.u >> 16);
}
__device__ __forceinline__ float bf16f(unsigned short h) {
    union { unsigned u; float f; } c; c.u = ((unsigned)h) << 16;
    return c.f;
}

// read 16B (8 bf16) from LDS as 2x b64 (rows are 8B-aligned)
__device__ __forceinline__ short8v lds_frag(const unsigned short* p) {
    union { unsigned u[4]; short8v v; } c;
    const uint2 a = *(const uint2*)p;
    const uint2 b = *(const uint2*)(p + 4);
    c.u[0] = a.x; c.u[1] = a.y; c.u[2] = b.x; c.u[3] = b.y;
    return c.v;
}

// ---------------------------------------------------------------------------
// Kernel 1: MFMA QKV projection with split-bf16 (hi/lo) operands.
// grid = (M/64, O/64), block 256 = 4 waves; wave (rw,cw) owns a 32x32
// quadrant = 2x2 16x16 MFMA tiles, for ALL THREE matrices (A-frag reuse x3).
// C = Ahi*Bhi + Ahi*Blo + Alo*Bhi (dropped term ~2^-16 relative).
// A (joint) read direct from global, split in registers (no LDS for A).
// W staged per-64-K-chunk into LDS transposed+split: Wt[n][e] hi/lo,
// stride 68 ushorts (8B-aligned rows; frag reads 2-way = free; stage writes
// 4-way = 1.58x on only 96 writes/block). W re-reads hit L2 (768 KB);
// joint re-reads across the 4 n-blocks hit L3 (67 MB << 256 MB).
// Outputs: q fp32 (to d_out), k split-bf16, v split-bf16 transposed [B][O][L].
// R5 lesson: no min-waves in __launch_bounds__ (VGPR cap -> scratch spill).
// ---------------------------------------------------------------------------
__global__ __launch_bounds__(256) void qkv_mfma(
    const float* __restrict__ joint, const float* __restrict__ Wq,
    const float* __restrict__ Wk, const float* __restrict__ Wv,
    float* __restrict__ qout,
    unsigned short* __restrict__ khi, unsigned short* __restrict__ klo,
    unsigned short* __restrict__ vthi, unsigned short* __restrict__ vtlo)
{
    const int m0 = blockIdx.x * 64;
    const int n0 = blockIdx.y * 64;
    const int tid  = threadIdx.x;
    const int lane = tid & 63;
    const int w    = tid >> 6;
    const int rw   = w >> 1;          // row half of the 64x64 tile
    const int cw   = w & 1;           // col half
    const int g    = lane >> 4;
    const int lr   = lane & 15;

    #define WSTR 68
    __shared__ unsigned short Wth[3][64][WSTR];
    __shared__ unsigned short Wtl[3][64][WSTR];

    const float* Wsrc[3] = {Wq, Wk, Wv};

    f32x4 acc[3][2][2];
    #pragma unroll
    for (int mat = 0; mat < 3; ++mat)
        #pragma unroll
        for (int rt = 0; rt < 2; ++rt)
            #pragma unroll
            for (int ct = 0; ct < 2; ++ct)
                acc[mat][rt][ct] = (f32x4){0.f, 0.f, 0.f, 0.f};

    for (int ec = 0; ec < 4; ++ec) {
        __syncthreads();   // previous chunk's frag reads done before overwrite
        {   // stage W chunk: transpose + split.  o = tid&63 (coalesced reads)
            const int o  = tid & 63;
            const int ee = (tid >> 6) * 2;   // 0,2,4,6
            #pragma unroll
            for (int mat = 0; mat < 3; ++mat) {
                const float* Wp = Wsrc[mat];
                #pragma unroll
                for (int pass = 0; pass < 8; ++pass) {
                    const int e = pass * 8 + ee;
                    const float w0 = Wp[(size_t)(ec * 64 + e) * OO + n0 + o];
                    const float w1 = Wp[(size_t)(ec * 64 + e + 1) * OO + n0 + o];
                    const unsigned short h0 = bf16h(w0), h1 = bf16h(w1);
                    const unsigned short l0 = bf16h(w0 - bf16f(h0));
                    const unsigned short l1 = bf16h(w1 - bf16f(h1));
                    *(unsigned*)&Wth[mat][o][e] = (unsigned)h0 | ((unsigned)h1 << 16);
                    *(unsigned*)&Wtl[mat][o][e] = (unsigned)l0 | ((unsigned)l1 << 16);
                }
            }
        }
        __syncthreads();

        #pragma unroll
        for (int sub = 0; sub < 2; ++sub) {   // K-step of 32 within the chunk
            short8v ah[2], al[2];
            #pragma unroll
            for (int rt = 0; rt < 2; ++rt) {
                const float* ap = joint + (size_t)(m0 + rw * 32 + rt * 16 + lr) * EE
                                        + ec * 64 + sub * 32 + g * 8;
                union { float4 q[2]; float f[8]; } aq;
                aq.q[0] = *(const float4*)ap;
                aq.q[1] = *(const float4*)(ap + 4);
                union { unsigned short s[8]; short8v v; } hi, lo;
                #pragma unroll
                for (int e = 0; e < 8; ++e) {
                    const unsigned short h = bf16h(aq.f[e]);
                    hi.s[e] = h;
                    lo.s[e] = bf16h(aq.f[e] - bf16f(h));
                }
                ah[rt] = hi.v; al[rt] = lo.v;
            }
            #pragma unroll
            for (int mat = 0; mat < 3; ++mat) {
                #pragma unroll
                for (int ct = 0; ct < 2; ++ct) {
                    const short8v bh = lds_frag(&Wth[mat][cw * 32 + ct * 16 + lr][sub * 32 + g * 8]);
                    const short8v bl = lds_frag(&Wtl[mat][cw * 32 + ct * 16 + lr][sub * 32 + g * 8]);
                    #pragma unroll
                    for (int rt = 0; rt < 2; ++rt) {
                        acc[mat][rt][ct] = MFMA16(ah[rt], bh, acc[mat][rt][ct]);
                        acc[mat][rt][ct] = MFMA16(ah[rt], bl, acc[mat][rt][ct]);
                        acc[mat][rt][ct] = MFMA16(al[rt], bh, acc[mat][rt][ct]);
                    }
                }
            }
        }
    }

    // ---- epilogue: q fp32; k split; v split transposed
    #pragma unroll
    for (int rt = 0; rt < 2; ++rt) {
        #pragma unroll
        for (int ct = 0; ct < 2; ++ct) {
            const int ocol = n0 + cw * 32 + ct * 16 + lr;
            #pragma unroll
            for (int r = 0; r < 4; ++r) {
                const int m = m0 + rw * 32 + rt * 16 + g * 4 + r;
                const size_t off = (size_t)m * OO + ocol;
                qout[off] = acc[0][rt][ct][r];
                const float kx = acc[1][rt][ct][r];
                const unsigned short kh = bf16h(kx);
                khi[off] = kh;
                klo[off] = bf16h(kx - bf16f(kh));
            }
            {   // v transposed: 4 consecutive m for fixed o -> ushort4
                const int bb   = m0 >> 10;
                const int mloc = (m0 & 1023) + rw * 32 + rt * 16 + g * 4;
                union { unsigned short s[4]; ushort4 v4; } h4, l4;
                #pragma unroll
                for (int r = 0; r < 4; ++r) {
                    const float vx = acc[2][rt][ct][r];
                    const unsigned short vh = bf16h(vx);
                    h4.s[r] = vh;
                    l4.s[r] = bf16h(vx - bf16f(vh));
                }
                const size_t toff = ((size_t)bb * OO + ocol) * LL + mloc;
                *(ushort4*)&vthi[toff] = h4.v4;
                *(ushort4*)&vtlo[toff] = l4.v4;
            }
        }
    }
}

// ---------------------------------------------------------------------------
// Kernel 2: MFMA flash attention with split-bf16 (hi/lo) operands.
// (unchanged from R7 — validated at ~285 us)
// ---------------------------------------------------------------------------
__global__ __launch_bounds__(256) void attn_mfma(
    const float* __restrict__ qm,
    const unsigned short* __restrict__ khi, const unsigned short* __restrict__ klo,
    const unsigned short* __restrict__ vthi, const unsigned short* __restrict__ vtlo,
    const float* __restrict__ delta, const int* __restrict__ traj_len,
    float* __restrict__ outp)
{
    const int b  = blockIdx.y;
    const int i0 = blockIdx.x * 32;
    const int T  = traj_len[b];
    const int tid  = threadIdx.x;
    const int lane = tid & 63;
    const int w    = tid >> 6;
    const int rh   = w >> 1;
    const int os   = w & 1;
    const int g    = lane >> 4;
    const int lr   = lane & 15;

    __shared__ unsigned short KVh[64][72];   // K e-chunk hi, then V^T hi (time-shared)
    __shared__ unsigned short KVl[64][72];   // lo counterpart
    __shared__ unsigned short Ph[32][72];    // P hi (bf16)
    __shared__ unsigned short Pl[32][72];    // P lo

    // ---- Q prologue: hi/lo A-fragments in registers (row = lr)
    short8v qhv[8], qlv[8];
    {
        const float* qrow = qm + (size_t)(b * LL + i0 + rh * 16 + lr) * OO;
        #pragma unroll
        for (int c = 0; c < 8; ++c) {
            union { float4 q[2]; float f[8]; } qq;
            qq.q[0] = *(const float4*)(qrow + c * 32 + g * 8);
            qq.q[1] = *(const float4*)(qrow + c * 32 + g * 8 + 4);
            union { unsigned short s[8]; short8v v; } hi, lo;
            #pragma unroll
            for (int e = 0; e < 8; ++e) {
                const unsigned short h = bf16h(qq.f[e]);
                hi.s[e] = h;
                lo.s[e] = bf16h(qq.f[e] - bf16f(h));
            }
            qhv[c] = hi.v; qlv[c] = lo.v;
        }
    }

    f32x4 o_acc[8];
    #pragma unroll
    for (int a = 0; a < 8; ++a) o_acc[a] = (f32x4){0.f, 0.f, 0.f, 0.f};
    float mrow[4] = {-INFINITY, -INFINITY, -INFINITY, -INFINITY};
    float lrow[4] = {0.f, 0.f, 0.f, 0.f};

    const int strow = tid >> 2;          // staging: row 0..63
    const int stcb  = (tid & 3) << 4;    // staging: col block 0/16/32/48

    for (int j0 = 0; j0 < LL; j0 += 64) {
        // ---- S init from delta bias (C-operand layout)
        f32x4 s_acc[4];
        #pragma unroll
        for (int ct = 0; ct < 4; ++ct) {
            const int j = j0 + ct * 16 + lr;
            #pragma unroll
            for (int r = 0; r < 4; ++r) {
                const int i = i0 + rh * 16 + g * 4 + r;
                const float2 d = *(const float2*)&delta[((size_t)(b * LL + i) * LL + j) * 2];
                s_acc[ct][r] = d.x + d.y;
            }
        }

        // ---- QK^T over e in 4 chunks of 64
        for (int ec = 0; ec < 4; ++ec) {
            __syncthreads();   // previous KV reads done before overwrite
            {
                const size_t src = ((size_t)(b * LL + j0 + strow)) * OO + ec * 64 + stcb;
                #pragma unroll
                for (int cc = 0; cc < 4; ++cc) {
                    *(uint2*)&KVh[strow][stcb + cc * 4] = *(const uint2*)&khi[src + cc * 4];
                    *(uint2*)&KVl[strow][stcb + cc * 4] = *(const uint2*)&klo[src + cc * 4];
                }
            }
            __syncthreads();
            #pragma unroll
            for (int sub = 0; sub < 2; ++sub) {
                const short8v qh = qhv[ec * 2 + sub];
                const short8v ql = qlv[ec * 2 + sub];
                #pragma unroll
                for (int ct = 0; ct < 4; ++ct) {
                    const short8v kh = lds_frag(&KVh[ct * 16 + lr][sub * 32 + g * 8]);
                    const short8v kl = lds_frag(&KVl[ct * 16 + lr][sub * 32 + g * 8]);
                    s_acc[ct] = MFMA16(qh, kh, s_acc[ct]);
                    s_acc[ct] = MFMA16(qh, kl, s_acc[ct]);
                    s_acc[ct] = MFMA16(ql, kh, s_acc[ct]);
                }
            }
        }

        // ---- online softmax (16-lane-group reduction; denominator unmasked)
        #pragma unroll
        for (int r = 0; r < 4; ++r) {
            float mx = fmaxf(fmaxf(s_acc[0][r], s_acc[1][r]),
                             fmaxf(s_acc[2][r], s_acc[3][r]));
            #pragma unroll
            for (int d = 1; d < 16; d <<= 1) mx = fmaxf(mx, __shfl_xor(mx, d));
            const float mnew = fmaxf(mrow[r], mx);
            const float sc = __expf(mrow[r] - mnew);
            float p[4], rs = 0.f;
            #pragma unroll
            for (int ct = 0; ct < 4; ++ct) { p[ct] = __expf(s_acc[ct][r] - mnew); rs += p[ct]; }
            #pragma unroll
            for (int d = 1; d < 16; d <<= 1) rs += __shfl_xor(rs, d);
            lrow[r] = lrow[r] * sc + rs;
            mrow[r] = mnew;
            const int prow = rh * 16 + g * 4 + r;
            #pragma unroll
            for (int ct = 0; ct < 4; ++ct) {
                const float pm = (j0 + ct * 16 + lr >= T) ? 0.f : p[ct];  // post-softmax mask
                const unsigned short h = bf16h(pm);
                Ph[prow][ct * 16 + lr] = h;
                Pl[prow][ct * 16 + lr] = bf16h(pm - bf16f(h));
            }
            #pragma unroll
            for (int a = 0; a < 8; ++a) o_acc[a][r] *= sc;
        }

        // ---- PV: 4 o-chunks of 64 (V^T staged hi/lo; barrier also orders P)
        for (int oc = 0; oc < 4; ++oc) {
            __syncthreads();
            {
                const size_t src = ((size_t)(b * OO + oc * 64 + strow)) * LL + j0 + stcb;
                #pragma unroll
                for (int cc = 0; cc < 4; ++cc) {
                    *(uint2*)&KVh[strow][stcb + cc * 4] = *(const uint2*)&vthi[src + cc * 4];
                    *(uint2*)&KVl[strow][stcb + cc * 4] = *(const uint2*)&vtlo[src + cc * 4];
                }
            }
            __syncthreads();
            #pragma unroll
            for (int jc = 0; jc < 2; ++jc) {
                const short8v ph = lds_frag(&Ph[rh * 16 + lr][jc * 32 + g * 8]);
                const short8v pl = lds_frag(&Pl[rh * 16 + lr][jc * 32 + g * 8]);
                #pragma unroll
                for (int t2 = 0; t2 < 2; ++t2) {
                    const int ct2 = os + 2 * t2;
                    const int a = oc * 2 + t2;
                    const short8v vh = lds_frag(&KVh[ct2 * 16 + lr][jc * 32 + g * 8]);
                    const short8v vl = lds_frag(&KVl[ct2 * 16 + lr][jc * 32 + g * 8]);
                    o_acc[a] = MFMA16(ph, vh, o_acc[a]);
                    o_acc[a] = MFMA16(ph, vl, o_acc[a]);
                    o_acc[a] = MFMA16(pl, vh, o_acc[a]);
                }
            }
        }
    }

    // ---- epilogue: normalize, zero invalid rows, store (own rows only)
    float inv[4];
    #pragma unroll
    for (int r = 0; r < 4; ++r) inv[r] = 1.f / lrow[r];
    #pragma unroll
    for (int oc = 0; oc < 4; ++oc) {
        #pragma unroll
        for (int t2 = 0; t2 < 2; ++t2) {
            const int a = oc * 2 + t2;
            const int o = oc * 64 + (os + 2 * t2) * 16 + lr;
            #pragma unroll
            for (int r = 0; r < 4; ++r) {
                const int i = i0 + rh * 16 + g * 4 + r;
                outp[(size_t)(b * LL + i) * OO + o] = (i < T) ? o_acc[a][r] * inv[r] : 0.f;
            }
        }
    }
}

// ---------------------------------------------------------------------------
extern "C" void kernel_launch(void* const* d_in, const int* in_sizes, int n_in,
                              void* d_out, int out_size, void* d_ws, size_t ws_size,
                              hipStream_t stream)
{
    const float* joint    = (const float*)d_in[0];
    const float* delta    = (const float*)d_in[1];
    const int*   traj_len = (const int*)d_in[2];
    const float* Wq       = (const float*)d_in[3];
    const float* Wk       = (const float*)d_in[4];
    const float* Wv       = (const float*)d_in[5];
    float* outp = (float*)d_out;

    const size_t stride = (size_t)BB * LL * OO;       // 4M elements
    float* q = outp;                                   // q fp32 in d_out
    unsigned short* khi  = (unsigned short*)d_ws;      // 8MB each
    unsigned short* klo  = khi + stride;
    unsigned short* vthi = klo + stride;
    unsigned short* vtlo = vthi + stride;              // total 32MB ws

    dim3 g1(BB * LL / 64, OO / 64);
    qkv_mfma<<<g1, 256, 0, stream>>>(joint, Wq, Wk, Wv, q, khi, klo, vthi, vtlo);

    dim3 g2(LL / 32, BB);
    attn_mfma<<<g2, 256, 0, stream>>>(q, khi, klo, vthi, vtlo, delta, traj_len, outp);
}